// Round 18
// baseline (3825.504 us; speedup 1.0000x reference)
//
#include <hip/hip_runtime.h>
#include <cstdint>
#include <cstddef>

#define S_LEN 256
#define BATCH 64
#define HID   1024
#define GATES 4096
#define NBLK  256
#define RING_D 4         // ring depth for BOTH h0 and h1

typedef _Float16 h16;
typedef _Float16 h16x8 __attribute__((ext_vector_type(8)));
typedef _Float16 h16x4 __attribute__((ext_vector_type(4)));
typedef float    f32x4 __attribute__((ext_vector_type(4)));

// ---------------------------------------------------------------------------
// x fp32 -> fp16 (one pass)
// ---------------------------------------------------------------------------
__global__ __launch_bounds__(256)
void xconv_kernel(const float* __restrict__ x, h16* __restrict__ x16)
{
  const int n4 = S_LEN * BATCH * HID / 4;
  const int stride = gridDim.x * 256;
  for (int i = blockIdx.x * 256 + threadIdx.x; i < n4; i += stride) {
    f32x4 v = ((const f32x4*)x)[i];
    h16x4 o;
    o[0] = (h16)v[0]; o[1] = (h16)v[1]; o[2] = (h16)v[2]; o[3] = (h16)v[3];
    ((h16x4*)x16)[i] = o;
  }
}

// ---------------------------------------------------------------------------
// Device-scope (sc1) 16B load: bypasses L1+L2, reads L3 coherence point.
// Issued without internal wait so batches pipeline; caller fences with
// vmcnt(0) + sched_barrier(0) before use (rule-18).
// ---------------------------------------------------------------------------
#define RLOAD(dst, ptr, OFFSTR)                                         \
  asm volatile("global_load_dwordx4 %0, %1, off offset:" OFFSTR " sc1"  \
               : "=&v"(dst) : "v"(ptr) : "memory")

// ---------------------------------------------------------------------------
// Compact epochs: group g = 128 u16 epochs in one 256B region (2 lines).
// wave_poll_c : whole-group poll (1 dword/lane). SLACK waits only.
// wave_poll_16: PRODUCER poll - wave w needs only blocks w*16..w*16+15
//               (its K-slice's producers) = 8 dwords = 1 cache line.
//               Lanes duplicate 8-wide; __all() reduces. Critical-path wait.
// Publishers: global_store_short sc1 (distinct bytes, write-through).
// ---------------------------------------------------------------------------
__device__ __forceinline__ void wave_poll_c(const unsigned* grp, unsigned tgt)
{
  const unsigned* p = grp + (threadIdx.x & 63);
  while (true) {
    const unsigned u = __hip_atomic_load(p, __ATOMIC_RELAXED,
                                         __HIP_MEMORY_SCOPE_AGENT);
    if ((u & 0xffffu) >= tgt && (u >> 16) >= tgt) break;
    __builtin_amdgcn_s_sleep(1);
  }
}

__device__ __forceinline__ void wave_poll_16(const unsigned* grp, int wave,
                                             unsigned tgt)
{
  const unsigned* p = grp + wave * 8 + (threadIdx.x & 7);
  while (true) {
    const unsigned u = __hip_atomic_load(p, __ATOMIC_RELAXED,
                                         __HIP_MEMORY_SCOPE_AGENT);
    const bool ok = ((u & 0xffffu) >= tgt) && ((u >> 16) >= tgt);
    if (__all(ok)) break;
    __builtin_amdgcn_s_sleep(1);
  }
}

// ---------------------------------------------------------------------------
// Persistent 2-layer decoupled-pipeline LSTM, producer-granular waits.
// 256 WGs x 512 thr. Group 0 = blocks 0..127 (layer 0), group 1 = layer 1.
// Wave w's K-slice [w*128,(w+1)*128) is produced by blocks w*16..w*16+15 of
// the source group, so critical waits are on 16 producers only; group-wide
// consensus is needed only for ring-slot overwrite, handled by slack waits
// (rings depth 4 -> slack >= 2 steps, off the critical path).
// Per iteration t:
//   SLACK  : own >= t-2 (t>=3); L0: oth >= t-3 (t>=4). [group-wide, compact]
//   SHADOW : accI = input-half partials (x16[t] / h0[t]); L1 waves first
//            producer-poll L0 16-producers >= t+1.
//   WAIT   : producer-poll own 16-producers >= t.
//   CRITICAL: load h_own[t-1] (16x16B sc1), 32 MFMAs on accI, 2-round 8-way
//            LDS reduce, activations, sc1 h stores, publish epoch t+1.
// LDS: 128KB weights + 32KB plds = exactly 160 KiB.
// No cache maintenance anywhere: mutable data all-sc1, immutable plain.
// ---------------------------------------------------------------------------
__global__ __launch_bounds__(512, 1)
void lstm_persistent(const h16* __restrict__ x16,
                     const float* __restrict__ weight,
                     const float* __restrict__ bias,
                     h16* __restrict__ h0r,
                     h16* __restrict__ h1r,
                     unsigned* __restrict__ ep)   // [2][64] uints = 2x256B
{
  __shared__ h16   wlds[65536];          // 128 KB
  __shared__ float plds[2][8][16][32];   // 32 KB

  const int wg    = blockIdx.x;
  const int layer = wg >> 7;
  const int j0    = (wg & 127) * 8;
  const int tid   = threadIdx.x;
  const int wave  = tid >> 6, lane = tid & 63;
  const int l15   = lane & 15, l16 = lane >> 4;
  const int BH    = BATCH * HID;

  // ---- one-time: pack weights fp32->fp16 into LDS ----
  // c = (((part*8 + w)*2 + n2)*4 + s)*64 + ln
  {
    const float* wsrc = weight + (size_t)layer * 2 * GATES * HID;
    for (int c = tid; c < 8192; c += 512) {
      const int ln = c & 63, s = (c >> 6) & 3, n2 = (c >> 8) & 1,
                w = (c >> 9) & 7, part = c >> 12;
      const int lc  = n2 * 16 + (ln & 15);              // local col 0..31
      const int col = (lc >> 3) * HID + j0 + (lc & 7);  // global gate col
      const int k   = w * 128 + s * 32 + (ln >> 4) * 8; // K within part
      const float* p = wsrc + (part ? (size_t)GATES * HID : (size_t)0)
                            + (size_t)col * HID + k;
      h16x8 v;
#pragma unroll
      for (int e = 0; e < 8; ++e) v[e] = (h16)p[e];
      *(h16x8*)&wlds[(size_t)c * 8] = v;
    }
  }
  // combined bias (threads 0-255 use it)
  float bc[4];
  {
    const int j = tid & 7;
#pragma unroll
    for (int gg = 0; gg < 4; ++gg) {
      const int col = gg * HID + j0 + j;
      bc[gg] = bias[(size_t)layer * 2 * GATES + col] +
               bias[(size_t)layer * 2 * GATES + GATES + col];
    }
  }
  float creg2[2] = {0.f, 0.f};   // thread tid<256: c for i = 2p + (tid>>7)
  __syncthreads();

  const unsigned* ep_own = ep + layer * 64;
  const unsigned* ep_oth = ep + (1 - layer) * 64;
  unsigned short* my_ep  = (unsigned short*)ep + (size_t)layer * 128 + (wg & 127);
  const h16* bbI = wlds + (size_t)wave * 4096 + lane * 8;  // input-part B
  const h16* bbH = bbI + 32768;                            // hidden-part B
  const int kw = wave * 128 + l16 * 8;                     // per-wave K base

  for (int t = 0; t < S_LEN; ++t) {
    // ========== SLACK (group-wide, ring-overwrite safety; >=2 steps) ======
    if (t >= 3) wave_poll_c(ep_own, (unsigned)(t - 2));
    if (layer == 0 && t >= RING_D) wave_poll_c(ep_oth, (unsigned)(t + 1 - RING_D));

    // ================= SHADOW: input-half partials for step t ==============
    const h16* As;
    if (layer == 0) {
      As = x16 + (size_t)t * BH;                       // always ready
    } else {
      wave_poll_16(ep_oth, wave, (unsigned)(t + 1));   // my 16 producers of h0[t]
      As = h0r + (size_t)(t % RING_D) * BH;
    }

    f32x4 accI[4][2];
#pragma unroll
    for (int i = 0; i < 4; ++i)
#pragma unroll
      for (int n2 = 0; n2 < 2; ++n2) accI[i][n2] = (f32x4)0.f;

#pragma unroll
    for (int sc = 0; sc < 2; ++sc) {
      h16x8 aS[2][4];
      if (layer == 0) {
#pragma unroll
        for (int ss = 0; ss < 2; ++ss)
#pragma unroll
          for (int i = 0; i < 4; ++i)
            aS[ss][i] = *(const h16x8*)(As + (size_t)(i * 16 + l15) * HID +
                                        kw + (sc * 2 + ss) * 32);
      } else {
#pragma unroll
        for (int i = 0; i < 4; ++i) {
          const h16* ap = As + (size_t)(i * 16 + l15) * HID + kw + sc * 64;
          RLOAD(aS[0][i], ap, "0");
          RLOAD(aS[1][i], ap, "64");
        }
        asm volatile("s_waitcnt vmcnt(0)" ::: "memory");
        __builtin_amdgcn_sched_barrier(0);
      }
#pragma unroll
      for (int ss = 0; ss < 2; ++ss) {
        const int s = sc * 2 + ss;
        const h16x8 b0 = *(const h16x8*)(bbI + s * 512);
        const h16x8 b1 = *(const h16x8*)(bbI + 2048 + s * 512);
#pragma unroll
        for (int i = 0; i < 4; ++i) {
          accI[i][0] = __builtin_amdgcn_mfma_f32_16x16x32_f16(aS[ss][i], b0, accI[i][0], 0, 0, 0);
          accI[i][1] = __builtin_amdgcn_mfma_f32_16x16x32_f16(aS[ss][i], b1, accI[i][1], 0, 0, 0);
        }
      }
    }

    // ================= WAIT (producer-granular): own h[t-1] ==============
    if (t) wave_poll_16(ep_own, wave, (unsigned)t);

    // ================= CRITICAL: hidden-half + reduce + publish ===========
    const h16* Ah;                    // h_own[t-1]
    h16* Hout;                        // h_own[t]
    if (layer == 0) {
      Ah   = h0r + (size_t)((t + RING_D - 1) % RING_D) * BH;
      Hout = h0r + (size_t)(t % RING_D) * BH;
    } else {
      Ah   = h1r + (size_t)((t + RING_D - 1) % RING_D) * BH;
      Hout = h1r + (size_t)(t % RING_D) * BH;
    }

    h16x8 aH[4][4];   // [row-tile i][k-chunk s]
#pragma unroll
    for (int i = 0; i < 4; ++i) {
      const h16* ap = Ah + (size_t)(i * 16 + l15) * HID + kw;
      RLOAD(aH[i][0], ap, "0");
      RLOAD(aH[i][1], ap, "64");
      RLOAD(aH[i][2], ap, "128");
      RLOAD(aH[i][3], ap, "192");
    }
    asm volatile("s_waitcnt vmcnt(0)" ::: "memory");
    __builtin_amdgcn_sched_barrier(0);

    f32x4 acc[4][2];
#pragma unroll
    for (int i = 0; i < 4; ++i)
#pragma unroll
      for (int n2 = 0; n2 < 2; ++n2) acc[i][n2] = accI[i][n2];

#pragma unroll
    for (int s = 0; s < 4; ++s) {
      const h16x8 b0 = *(const h16x8*)(bbH + s * 512);
      const h16x8 b1 = *(const h16x8*)(bbH + 2048 + s * 512);
#pragma unroll
      for (int i = 0; i < 4; ++i) {
        acc[i][0] = __builtin_amdgcn_mfma_f32_16x16x32_f16(aH[i][s], b0, acc[i][0], 0, 0, 0);
        acc[i][1] = __builtin_amdgcn_mfma_f32_16x16x32_f16(aH[i][s], b1, acc[i][1], 0, 0, 0);
      }
    }

    // ---- 8-way cross-wave reduce, 2 rounds of 2 m-tiles (4 syncthreads) ---
#pragma unroll
    for (int p = 0; p < 2; ++p) {
#pragma unroll
      for (int ii = 0; ii < 2; ++ii) {
        const int i = p * 2 + ii;
#pragma unroll
        for (int n2 = 0; n2 < 2; ++n2)
#pragma unroll
          for (int q = 0; q < 4; ++q) {
            const int r = l16 * 4 + q;                        // 0..15
            const int colS = (n2 * 16 + l15) ^ ((r & 7) << 2);
            plds[ii][wave][r][colS] = acc[i][n2][q];
          }
      }
      __syncthreads();
      if (tid < 256) {
        const int ii = tid >> 7, r = (tid >> 3) & 15, j = tid & 7;
        float gv[4];
#pragma unroll
        for (int gg = 0; gg < 4; ++gg) {
          const int colS = (gg * 8 + j) ^ ((r & 7) << 2);
          float s = bc[gg];
#pragma unroll
          for (int w = 0; w < 8; ++w) s += plds[ii][w][r][colS];
          gv[gg] = s;
        }
        const float ig = 1.f / (1.f + __expf(-gv[0]));
        const float fg = 1.f / (1.f + __expf(-gv[1]));
        const float gt = 1.f - 2.f / (__expf(2.f * gv[2]) + 1.f);
        const float og = 1.f / (1.f + __expf(-gv[3]));
        const float cn = fg * creg2[p] + ig * gt;
        creg2[p] = cn;
        const float th = 1.f - 2.f / (__expf(2.f * cn) + 1.f);
        union { h16 f; unsigned short u; } hb;
        hb.f = (h16)(og * th);
        const int row = (p * 2 + ii) * 16 + r;
        __hip_atomic_store(
            (unsigned short*)&Hout[(size_t)row * HID + j0 + j],
            hb.u, __ATOMIC_RELAXED, __HIP_MEMORY_SCOPE_AGENT);
      }
      __syncthreads();   // drains each wave's vmcnt: h-stores at L3
    }

    // ---- publish step completion: u16 epoch into the compact line ----
    if (tid == 0)
      asm volatile("global_store_short %0, %1, off sc1"
                   :: "v"(my_ep), "v"(t + 1) : "memory");
  }
}

// ---------------------------------------------------------------------------
// out[m][cls] = h[m] . fc_w[cls] + fc_b[cls]. One wave per output.
// ---------------------------------------------------------------------------
__global__ __launch_bounds__(256)
void fc_kernel(const h16* __restrict__ h,
               const float* __restrict__ fw,
               const float* __restrict__ fb,
               float* __restrict__ out)
{
  const int gw = (blockIdx.x * blockDim.x + threadIdx.x) >> 6;
  const int lane = threadIdx.x & 63;
  if (gw >= BATCH * 10) return;
  const int m = gw / 10, cls = gw % 10;
  float s = 0.f;
  for (int k = lane; k < HID; k += 64)
    s += (float)h[(size_t)m * HID + k] * fw[(size_t)cls * HID + k];
#pragma unroll
  for (int off = 32; off; off >>= 1) s += __shfl_down(s, off);
  if (lane == 0) out[m * 10 + cls] = s + fb[cls];
}

// ---------------------------------------------------------------------------
extern "C" void kernel_launch(void* const* d_in, const int* in_sizes, int n_in,
                              void* d_out, int out_size, void* d_ws, size_t ws_size,
                              hipStream_t stream)
{
  const float* x      = (const float*)d_in[0];   // [256][64][1024]
  const float* weight = (const float*)d_in[1];   // [2][2][4096][1024]
  const float* bias   = (const float*)d_in[2];   // [2][2][4096]
  const float* fc_w   = (const float*)d_in[3];   // [10][1024]
  const float* fc_b   = (const float*)d_in[4];   // [10]
  float* out = (float*)d_out;                    // [64][10]

  auto align = [](size_t v) { return (v + 255) & ~(size_t)255; };
  const size_t ep_sz   = 512;                                              // 2x256B
  const size_t x16_sz  = (size_t)S_LEN * BATCH * HID * sizeof(h16);        // 32 MB
  const size_t h0r_sz  = (size_t)RING_D * BATCH * HID * sizeof(h16);       // 512 KB
  const size_t h1r_sz  = (size_t)RING_D * BATCH * HID * sizeof(h16);       // 512 KB

  char* p = (char*)d_ws;
  unsigned* ep = (unsigned*)p; p += align(ep_sz);
  h16* x16 = (h16*)p; p += align(x16_sz);
  h16* h0r = (h16*)p; p += align(h0r_sz);
  h16* h1r = (h16*)p; p += align(h1r_sz);

  hipMemsetAsync(ep, 0, ep_sz, stream);
  hipMemsetAsync(h0r, 0, h0r_sz, stream);
  hipMemsetAsync(h1r, 0, h1r_sz, stream);

  xconv_kernel<<<dim3(2048), 256, 0, stream>>>(x, x16);

  lstm_persistent<<<dim3(NBLK), dim3(512), 0, stream>>>(
      x16, weight, bias, h0r, h1r, ep);

  // final h of top layer: t = 255 -> h1 ring slot (255 % 4) = 3
  fc_kernel<<<dim3((BATCH * 10 * 64) / 256), 256, 0, stream>>>(
      h1r + (size_t)((S_LEN - 1) % RING_D) * BATCH * HID, fc_w, fc_b, out);
}

// Round 19
// 3000.842 us; speedup vs baseline: 1.2748x; 1.2748x over previous
//
#include <hip/hip_runtime.h>
#include <cstdint>
#include <cstddef>

#define S_LEN 256
#define BATCH 64
#define HID   1024
#define GATES 4096
#define NBLK  128        // 64 blocks per layer
#define RING_D 4         // h0 ring depth (h1 ring depth 2)

typedef _Float16 h16;
typedef _Float16 h16x8 __attribute__((ext_vector_type(8)));
typedef _Float16 h16x4 __attribute__((ext_vector_type(4)));
typedef float    f32x4 __attribute__((ext_vector_type(4)));

// ---------------------------------------------------------------------------
// x fp32 -> fp16 (one pass)
// ---------------------------------------------------------------------------
__global__ __launch_bounds__(256)
void xconv_kernel(const float* __restrict__ x, h16* __restrict__ x16)
{
  const int n4 = S_LEN * BATCH * HID / 4;
  const int stride = gridDim.x * 256;
  for (int i = blockIdx.x * 256 + threadIdx.x; i < n4; i += stride) {
    f32x4 v = ((const f32x4*)x)[i];
    h16x4 o;
    o[0] = (h16)v[0]; o[1] = (h16)v[1]; o[2] = (h16)v[2]; o[3] = (h16)v[3];
    ((h16x4*)x16)[i] = o;
  }
}

// ---------------------------------------------------------------------------
// W_ih (both layers) fp32 -> fp16, natural [layer][4096][1024] layout.
// Stays L2-resident during the persistent kernel (2 MB slice per XCD).
// ---------------------------------------------------------------------------
__global__ __launch_bounds__(256)
void wconv_kernel(const float* __restrict__ weight, h16* __restrict__ wih16)
{
  const int n4 = 2 * GATES * HID / 4;          // 2M x4-vectors
  const int stride = gridDim.x * 256;
  for (int i = blockIdx.x * 256 + threadIdx.x; i < n4; i += stride) {
    const int e = i * 4;
    const int l = e >> 22;                      // 4M elems per layer
    const int r = e & ((GATES * HID) - 1);
    f32x4 v = *(const f32x4*)(weight + (size_t)l * 2 * GATES * HID + r);
    h16x4 o;
    o[0] = (h16)v[0]; o[1] = (h16)v[1]; o[2] = (h16)v[2]; o[3] = (h16)v[3];
    *(h16x4*)(wih16 + (size_t)l * GATES * HID + r) = o;
  }
}

// ---------------------------------------------------------------------------
// Device-scope (sc1) 16B load: bypasses L1+L2, reads L3 coherence point.
// Issued without internal wait so batches pipeline; caller fences with
// vmcnt(0) + sched_barrier(0) before use (rule-18).
// ---------------------------------------------------------------------------
#define RLOAD(dst, ptr, OFFSTR)                                         \
  asm volatile("global_load_dwordx4 %0, %1, off offset:" OFFSTR " sc1"  \
               : "=&v"(dst) : "v"(ptr) : "memory")

// ---------------------------------------------------------------------------
// Compact epoch poll: a group's 64 blocks each own a u16 epoch in ONE 128B
// cache line (32 dwords). Lane l checks dword (l&31) = epochs 2l,2l+1; all
// lanes must pass -> group consensus in a single line poll.
// Publishers: global_store_short sc1 (distinct bytes, write-through).
// ---------------------------------------------------------------------------
__device__ __forceinline__ void wave_poll_c(const unsigned* grp, unsigned tgt)
{
  const unsigned* p = grp + (threadIdx.x & 31);
  while (true) {
    const unsigned u = __hip_atomic_load(p, __ATOMIC_RELAXED,
                                         __HIP_MEMORY_SCOPE_AGENT);
    if ((u & 0xffffu) >= tgt && (u >> 16) >= tgt) break;
    __builtin_amdgcn_s_sleep(1);
  }
}

// ---------------------------------------------------------------------------
// Persistent 2-layer decoupled-pipeline LSTM, 64 BLOCKS PER LAYER.
// 128 WGs x 512 thr. Group 0 = blocks 0..63 (layer 0), group 1 = layer 1.
// WG owns 16 h-cols j0..j0+15 => 64 gate-cols = 4 n-tiles (one per gate).
// Wave w owns K-slice [w*128,(w+1)*128).
// Halving the consumer count halves the per-step L3 broadcast traffic
// (48 -> 24 MB/step): W_hh (critical) in 128KB LDS; W_ih (shadow) read
// from L2-resident fp16 copy each step.
// Per iteration t (R16 wait logic):
//   SHADOW : acc = x16[t] @ W_ih^T (L0, plain loads) or h0[t] @ W_ih^T
//            (L1, sc1; first poll L0 epochs >= t+1). B from L2.
//   WAIT   : own epochs >= t; L0 also: L1 >= t+1-RING_D (h0 slot safety).
//   CRITICAL: load h_own[t-1] (16x16B sc1), 64 MFMA on acc, 4-round 8-way
//            LDS reduce (16 rows x 64 gate-cols each), activations, sc1 h
//            stores, publish epoch t+1.
// LDS: 128KB W_hh + 32KB plds = exactly 160 KiB.
// No cache maintenance anywhere: mutable data all-sc1, immutable plain.
// ---------------------------------------------------------------------------
__global__ __launch_bounds__(512, 1)
void lstm_persistent(const h16* __restrict__ x16,
                     const h16* __restrict__ wih16,
                     const float* __restrict__ weight,
                     const float* __restrict__ bias,
                     h16* __restrict__ h0r,
                     h16* __restrict__ h1r,
                     unsigned* __restrict__ ep)   // [2][32] uints = 2x128B
{
  __shared__ h16   wlds[65536];          // 128 KB: [8 w][4 g][4 s][64 ln][8]
  __shared__ float plds[8][16][64];      // 32 KB

  const int wg    = blockIdx.x;
  const int layer = wg >> 6;
  const int j0    = (wg & 63) * 16;
  const int tid   = threadIdx.x;
  const int wave  = tid >> 6, lane = tid & 63;
  const int l15   = lane & 15, l16 = lane >> 4;
  const int BH    = BATCH * HID;

  // ---- one-time: pack W_hh slice fp32->fp16 into LDS ----
  // c = ((w*4 + g)*4 + s)*64 + ln
  {
    const float* whh = weight + (size_t)layer * 2 * GATES * HID
                              + (size_t)GATES * HID;
    for (int c = tid; c < 8192; c += 512) {
      const int ln = c & 63, s = (c >> 6) & 3, g = (c >> 8) & 3, w = c >> 10;
      const int col = g * HID + j0 + (ln & 15);
      const int k   = w * 128 + s * 32 + (ln >> 4) * 8;
      const float* p = whh + (size_t)col * HID + k;
      h16x8 v;
#pragma unroll
      for (int e = 0; e < 8; ++e) v[e] = (h16)p[e];
      *(h16x8*)&wlds[(size_t)c * 8] = v;
    }
  }
  // combined bias (threads 0-255 use it): col j0 + (tid&15) per gate
  float bc[4];
  {
    const int jj = tid & 15;
#pragma unroll
    for (int gg = 0; gg < 4; ++gg) {
      const int col = gg * HID + j0 + jj;
      bc[gg] = bias[(size_t)layer * 2 * GATES + col] +
               bias[(size_t)layer * 2 * GATES + GATES + col];
    }
  }
  float creg[4] = {0.f, 0.f, 0.f, 0.f};  // thread (r,jj): c for row p*16+r
  __syncthreads();

  const unsigned* ep_own = ep + layer * 32;
  const unsigned* ep_oth = ep + (1 - layer) * 32;
  unsigned short* my_ep  = (unsigned short*)ep + (size_t)layer * 64 + (wg & 63);
  const h16* wih = wih16 + (size_t)layer * GATES * HID;
  const h16* bbH = wlds + (size_t)wave * 8192 + lane * 8;  // (g,s): +(g*4+s)*512
  const int kw = wave * 128 + l16 * 8;                     // per-wave K base

  for (int t = 0; t < S_LEN; ++t) {
    // ================= SHADOW: input-half partials for step t ==============
    const h16* As;
    if (layer == 0) {
      As = x16 + (size_t)t * BH;                       // always ready
    } else {
      wave_poll_c(ep_oth, (unsigned)(t + 1));          // h0[t] ready
      As = h0r + (size_t)(t % RING_D) * BH;
    }

    // B-frags from L2 (plain) + A-frags; one batched issue, one wait.
    h16x8 aS[4][4], bS[4][4];
#pragma unroll
    for (int g = 0; g < 4; ++g) {
      const h16* bp = wih + (size_t)(g * HID + j0 + l15) * HID + kw;
#pragma unroll
      for (int s = 0; s < 4; ++s) bS[g][s] = *(const h16x8*)(bp + s * 32);
    }
    if (layer == 0) {
#pragma unroll
      for (int i = 0; i < 4; ++i) {
        const h16* ap = As + (size_t)(i * 16 + l15) * HID + kw;
#pragma unroll
        for (int s = 0; s < 4; ++s) aS[i][s] = *(const h16x8*)(ap + s * 32);
      }
    } else {
#pragma unroll
      for (int i = 0; i < 4; ++i) {
        const h16* ap = As + (size_t)(i * 16 + l15) * HID + kw;
        RLOAD(aS[i][0], ap, "0");
        RLOAD(aS[i][1], ap, "64");
        RLOAD(aS[i][2], ap, "128");
        RLOAD(aS[i][3], ap, "192");
      }
      asm volatile("s_waitcnt vmcnt(0)" ::: "memory");
      __builtin_amdgcn_sched_barrier(0);
    }

    f32x4 acc[4][4];   // [m-tile i][gate g]
#pragma unroll
    for (int i = 0; i < 4; ++i)
#pragma unroll
      for (int g = 0; g < 4; ++g) acc[i][g] = (f32x4)0.f;

#pragma unroll
    for (int s = 0; s < 4; ++s)
#pragma unroll
      for (int i = 0; i < 4; ++i)
#pragma unroll
        for (int g = 0; g < 4; ++g)
          acc[i][g] = __builtin_amdgcn_mfma_f32_16x16x32_f16(aS[i][s], bS[g][s],
                                                             acc[i][g], 0, 0, 0);

    // ================= WAIT: own @ t; L0 h0-ring safety ===================
    if (t) wave_poll_c(ep_own, (unsigned)t);
    if (layer == 0 && t >= RING_D) wave_poll_c(ep_oth, (unsigned)(t + 1 - RING_D));

    // ================= CRITICAL: hidden-half + reduce + publish ===========
    const h16* Ah;                    // h_own[t-1]
    h16* Hout;                        // h_own[t]
    if (layer == 0) {
      Ah   = h0r + (size_t)((t + RING_D - 1) % RING_D) * BH;
      Hout = h0r + (size_t)(t % RING_D) * BH;
    } else {
      Ah   = h1r + (size_t)((t + 1) & 1) * BH;
      Hout = h1r + (size_t)(t & 1) * BH;
    }

    h16x8 aH[4][4];   // [m-tile i][k-chunk s]
#pragma unroll
    for (int i = 0; i < 4; ++i) {
      const h16* ap = Ah + (size_t)(i * 16 + l15) * HID + kw;
      RLOAD(aH[i][0], ap, "0");
      RLOAD(aH[i][1], ap, "64");
      RLOAD(aH[i][2], ap, "128");
      RLOAD(aH[i][3], ap, "192");
    }
    asm volatile("s_waitcnt vmcnt(0)" ::: "memory");
    __builtin_amdgcn_sched_barrier(0);

#pragma unroll
    for (int s = 0; s < 4; ++s)
#pragma unroll
      for (int g = 0; g < 4; ++g) {
        const h16x8 b = *(const h16x8*)(bbH + (g * 4 + s) * 512);
#pragma unroll
        for (int i = 0; i < 4; ++i)
          acc[i][g] = __builtin_amdgcn_mfma_f32_16x16x32_f16(aH[i][s], b,
                                                             acc[i][g], 0, 0, 0);
      }

    // ---- 8-way cross-wave reduce, 4 rounds of 16 rows x 64 gate-cols ----
#pragma unroll
    for (int p = 0; p < 4; ++p) {
#pragma unroll
      for (int g = 0; g < 4; ++g)
#pragma unroll
        for (int q = 0; q < 4; ++q) {
          const int r = l16 * 4 + q;                        // 0..15
          const int colS = (g * 16 + l15) ^ ((r & 7) << 2);
          plds[wave][r][colS] = acc[p][g][q];
        }
      __syncthreads();
      if (tid < 256) {
        const int r = tid >> 4, jj = tid & 15;
        float gv[4];
#pragma unroll
        for (int gg = 0; gg < 4; ++gg) {
          const int colS = (gg * 16 + jj) ^ ((r & 7) << 2);
          float s = bc[gg];
#pragma unroll
          for (int w = 0; w < 8; ++w) s += plds[w][r][colS];
          gv[gg] = s;
        }
        const float ig = 1.f / (1.f + __expf(-gv[0]));
        const float fg = 1.f / (1.f + __expf(-gv[1]));
        const float gt = 1.f - 2.f / (__expf(2.f * gv[2]) + 1.f);
        const float og = 1.f / (1.f + __expf(-gv[3]));
        const float cn = fg * creg[p] + ig * gt;
        creg[p] = cn;
        const float th = 1.f - 2.f / (__expf(2.f * cn) + 1.f);
        union { h16 f; unsigned short u; } hb;
        hb.f = (h16)(og * th);
        const int row = p * 16 + r;
        __hip_atomic_store(
            (unsigned short*)&Hout[(size_t)row * HID + j0 + jj],
            hb.u, __ATOMIC_RELAXED, __HIP_MEMORY_SCOPE_AGENT);
      }
      __syncthreads();   // drains each wave's vmcnt: h-stores at L3
    }

    // ---- publish step completion: u16 epoch into the compact line ----
    if (tid == 0)
      asm volatile("global_store_short %0, %1, off sc1"
                   :: "v"(my_ep), "v"(t + 1) : "memory");
  }
}

// ---------------------------------------------------------------------------
// out[m][cls] = h[m] . fc_w[cls] + fc_b[cls]. One wave per output.
// ---------------------------------------------------------------------------
__global__ __launch_bounds__(256)
void fc_kernel(const h16* __restrict__ h,
               const float* __restrict__ fw,
               const float* __restrict__ fb,
               float* __restrict__ out)
{
  const int gw = (blockIdx.x * blockDim.x + threadIdx.x) >> 6;
  const int lane = threadIdx.x & 63;
  if (gw >= BATCH * 10) return;
  const int m = gw / 10, cls = gw % 10;
  float s = 0.f;
  for (int k = lane; k < HID; k += 64)
    s += (float)h[(size_t)m * HID + k] * fw[(size_t)cls * HID + k];
#pragma unroll
  for (int off = 32; off; off >>= 1) s += __shfl_down(s, off);
  if (lane == 0) out[m * 10 + cls] = s + fb[cls];
}

// ---------------------------------------------------------------------------
extern "C" void kernel_launch(void* const* d_in, const int* in_sizes, int n_in,
                              void* d_out, int out_size, void* d_ws, size_t ws_size,
                              hipStream_t stream)
{
  const float* x      = (const float*)d_in[0];   // [256][64][1024]
  const float* weight = (const float*)d_in[1];   // [2][2][4096][1024]
  const float* bias   = (const float*)d_in[2];   // [2][2][4096]
  const float* fc_w   = (const float*)d_in[3];   // [10][1024]
  const float* fc_b   = (const float*)d_in[4];   // [10]
  float* out = (float*)d_out;                    // [64][10]

  auto align = [](size_t v) { return (v + 255) & ~(size_t)255; };
  const size_t ep_sz    = 512;
  const size_t x16_sz   = (size_t)S_LEN * BATCH * HID * sizeof(h16);       // 32 MB
  const size_t wih_sz   = (size_t)2 * GATES * HID * sizeof(h16);          // 16 MB
  const size_t h0r_sz   = (size_t)RING_D * BATCH * HID * sizeof(h16);     // 512 KB
  const size_t h1r_sz   = (size_t)2 * BATCH * HID * sizeof(h16);          // 256 KB

  char* p = (char*)d_ws;
  unsigned* ep = (unsigned*)p; p += align(ep_sz);
  h16* x16   = (h16*)p; p += align(x16_sz);
  h16* wih16 = (h16*)p; p += align(wih_sz);
  h16* h0r   = (h16*)p; p += align(h0r_sz);
  h16* h1r   = (h16*)p; p += align(h1r_sz);

  hipMemsetAsync(ep, 0, ep_sz, stream);
  hipMemsetAsync(h0r, 0, h0r_sz, stream);
  hipMemsetAsync(h1r, 0, h1r_sz, stream);

  xconv_kernel<<<dim3(2048), 256, 0, stream>>>(x, x16);
  wconv_kernel<<<dim3(2048), 256, 0, stream>>>(weight, wih16);

  lstm_persistent<<<dim3(NBLK), dim3(512), 0, stream>>>(
      x16, wih16, weight, bias, h0r, h1r, ep);

  // final h of top layer: t = 255 -> h1 ring slot 1
  fc_kernel<<<dim3((BATCH * 10 * 64) / 256), 256, 0, stream>>>(
      h1r + (size_t)BATCH * HID, fc_w, fc_b, out);
}

// Round 20
// 2409.401 us; speedup vs baseline: 1.5877x; 1.2455x over previous
//
#include <hip/hip_runtime.h>
#include <cstdint>
#include <cstddef>

#define S_LEN 256
#define BATCH 64
#define HID   1024
#define GATES 4096
#define NBLK  256
#define RING_D 4         // h0 ring depth

typedef _Float16 h16;
typedef _Float16 h16x8 __attribute__((ext_vector_type(8)));
typedef _Float16 h16x4 __attribute__((ext_vector_type(4)));
typedef float    f32x4 __attribute__((ext_vector_type(4)));

// ---------------------------------------------------------------------------
// x fp32 -> fp16 (one pass)
// ---------------------------------------------------------------------------
__global__ __launch_bounds__(256)
void xconv_kernel(const float* __restrict__ x, h16* __restrict__ x16)
{
  const int n4 = S_LEN * BATCH * HID / 4;
  const int stride = gridDim.x * 256;
  for (int i = blockIdx.x * 256 + threadIdx.x; i < n4; i += stride) {
    f32x4 v = ((const f32x4*)x)[i];
    h16x4 o;
    o[0] = (h16)v[0]; o[1] = (h16)v[1]; o[2] = (h16)v[2]; o[3] = (h16)v[3];
    ((h16x4*)x16)[i] = o;
  }
}

// ---------------------------------------------------------------------------
// Device-scope (sc1) 16B load: bypasses L1+L2, reads L3 coherence point.
// Issued without internal wait so batches pipeline; caller fences with
// vmcnt(0) + sched_barrier(0) before use (rule-18).
// ---------------------------------------------------------------------------
#define RLOAD(dst, ptr, OFFSTR)                                         \
  asm volatile("global_load_dwordx4 %0, %1, off offset:" OFFSTR " sc1"  \
               : "=&v"(dst) : "v"(ptr) : "memory")

// ---------------------------------------------------------------------------
// COMPACT epoch poll: group g's 128 blocks each own a u16 epoch in ONE 256B
// region (2 cache lines). A wave polls the whole group with a single dword
// load per lane (lane i checks epochs 2i, 2i+1). Total poll footprint per
// iteration: 2 lines (vs 128 padded lines before) -> ~64x less L3 request
// pressure. Publishers use global_store_short sc1 (distinct bytes, race-free,
// write-through to L3). Epochs <= 256 fit u16.
// ---------------------------------------------------------------------------
__device__ __forceinline__ void wave_poll_c(const unsigned* grp, unsigned tgt)
{
  const unsigned* p = grp + (threadIdx.x & 63);
  while (true) {
    const unsigned u = __hip_atomic_load(p, __ATOMIC_RELAXED,
                                         __HIP_MEMORY_SCOPE_AGENT);
    if ((u & 0xffffu) >= tgt && (u >> 16) >= tgt) break;
    __builtin_amdgcn_s_sleep(1);
  }
}

// ---------------------------------------------------------------------------
// Persistent 2-layer decoupled-pipeline LSTM (R14 structure + compact flags).
// 256 WGs x 512 thr. Group 0 = blocks 0..127 (layer 0), group 1 = layer 1.
// Per iteration t:
//   SHADOW : accI = input-half partials (x16[t] / h0[t]); L1 waves first
//            compact-poll L0 epochs >= t+1.
//   WAIT   : compact-poll own epochs >= t; L0 also polls L1 >= t+1-RING_D.
//   CRITICAL: load h_own[t-1] (16x16B sc1), 32 MFMAs on accI, 2-round 8-way
//            LDS reduce, activations, sc1 h stores, publish epoch t+1.
// LDS: 128KB weights + 32KB plds = exactly 160 KiB.
// No cache maintenance anywhere: mutable data all-sc1, immutable plain.
// ---------------------------------------------------------------------------
__global__ __launch_bounds__(512, 1)
void lstm_persistent(const h16* __restrict__ x16,
                     const float* __restrict__ weight,
                     const float* __restrict__ bias,
                     h16* __restrict__ h0r,
                     h16* __restrict__ h1r,
                     unsigned* __restrict__ ep)   // [2][64] uints = 2x256B
{
  __shared__ h16   wlds[65536];          // 128 KB
  __shared__ float plds[2][8][16][32];   // 32 KB

  const int wg    = blockIdx.x;
  const int layer = wg >> 7;
  const int j0    = (wg & 127) * 8;
  const int tid   = threadIdx.x;
  const int wave  = tid >> 6, lane = tid & 63;
  const int l15   = lane & 15, l16 = lane >> 4;
  const int BH    = BATCH * HID;

  // ---- one-time: pack weights fp32->fp16 into LDS ----
  // c = (((part*8 + w)*2 + n2)*4 + s)*64 + ln
  {
    const float* wsrc = weight + (size_t)layer * 2 * GATES * HID;
    for (int c = tid; c < 8192; c += 512) {
      const int ln = c & 63, s = (c >> 6) & 3, n2 = (c >> 8) & 1,
                w = (c >> 9) & 7, part = c >> 12;
      const int lc  = n2 * 16 + (ln & 15);              // local col 0..31
      const int col = (lc >> 3) * HID + j0 + (lc & 7);  // global gate col
      const int k   = w * 128 + s * 32 + (ln >> 4) * 8; // K within part
      const float* p = wsrc + (part ? (size_t)GATES * HID : (size_t)0)
                            + (size_t)col * HID + k;
      h16x8 v;
#pragma unroll
      for (int e = 0; e < 8; ++e) v[e] = (h16)p[e];
      *(h16x8*)&wlds[(size_t)c * 8] = v;
    }
  }
  // combined bias (threads 0-255 use it)
  float bc[4];
  {
    const int j = tid & 7;
#pragma unroll
    for (int gg = 0; gg < 4; ++gg) {
      const int col = gg * HID + j0 + j;
      bc[gg] = bias[(size_t)layer * 2 * GATES + col] +
               bias[(size_t)layer * 2 * GATES + GATES + col];
    }
  }
  float creg2[2] = {0.f, 0.f};   // thread tid<256: c for i = 2p + (tid>>7)
  __syncthreads();

  const unsigned* ep_own = ep + layer * 64;
  const unsigned* ep_oth = ep + (1 - layer) * 64;
  unsigned short* my_ep  = (unsigned short*)ep + (size_t)layer * 128 + (wg & 127);
  const h16* bbI = wlds + (size_t)wave * 4096 + lane * 8;  // input-part B
  const h16* bbH = bbI + 32768;                            // hidden-part B
  const int kw = wave * 128 + l16 * 8;                     // per-wave K base

  for (int t = 0; t < S_LEN; ++t) {
    // ================= SHADOW: input-half partials for step t ==============
    const h16* As;
    if (layer == 0) {
      As = x16 + (size_t)t * BH;                       // always ready
    } else {
      wave_poll_c(ep_oth, (unsigned)(t + 1));          // h0[t] ready
      As = h0r + (size_t)(t % RING_D) * BH;
    }

    f32x4 accI[4][2];
#pragma unroll
    for (int i = 0; i < 4; ++i)
#pragma unroll
      for (int n2 = 0; n2 < 2; ++n2) accI[i][n2] = (f32x4)0.f;

#pragma unroll
    for (int sc = 0; sc < 2; ++sc) {
      h16x8 aS[2][4];
      if (layer == 0) {
#pragma unroll
        for (int ss = 0; ss < 2; ++ss)
#pragma unroll
          for (int i = 0; i < 4; ++i)
            aS[ss][i] = *(const h16x8*)(As + (size_t)(i * 16 + l15) * HID +
                                        kw + (sc * 2 + ss) * 32);
      } else {
#pragma unroll
        for (int i = 0; i < 4; ++i) {
          const h16* ap = As + (size_t)(i * 16 + l15) * HID + kw + sc * 64;
          RLOAD(aS[0][i], ap, "0");
          RLOAD(aS[1][i], ap, "64");
        }
        asm volatile("s_waitcnt vmcnt(0)" ::: "memory");
        __builtin_amdgcn_sched_barrier(0);
      }
#pragma unroll
      for (int ss = 0; ss < 2; ++ss) {
        const int s = sc * 2 + ss;
        const h16x8 b0 = *(const h16x8*)(bbI + s * 512);
        const h16x8 b1 = *(const h16x8*)(bbI + 2048 + s * 512);
#pragma unroll
        for (int i = 0; i < 4; ++i) {
          accI[i][0] = __builtin_amdgcn_mfma_f32_16x16x32_f16(aS[ss][i], b0, accI[i][0], 0, 0, 0);
          accI[i][1] = __builtin_amdgcn_mfma_f32_16x16x32_f16(aS[ss][i], b1, accI[i][1], 0, 0, 0);
        }
      }
    }

    // ================= WAIT (compact): own @ t; L0 ring safety ============
    if (t) wave_poll_c(ep_own, (unsigned)t);
    if (layer == 0) {
      const int ct = t + 1 - RING_D;
      if (ct > 0) wave_poll_c(ep_oth, (unsigned)ct);
    }

    // ================= CRITICAL: hidden-half + reduce + publish ===========
    const h16* Ah;                    // h_own[t-1]
    h16* Hout;                        // h_own[t]
    if (layer == 0) {
      Ah   = h0r + (size_t)((t + RING_D - 1) % RING_D) * BH;
      Hout = h0r + (size_t)(t % RING_D) * BH;
    } else {
      Ah   = h1r + (size_t)((t + 1) & 1) * BH;
      Hout = h1r + (size_t)(t & 1) * BH;
    }

    h16x8 aH[4][4];
#pragma unroll
    for (int i = 0; i < 4; ++i) {
      const h16* ap = Ah + (size_t)(i * 16 + l15) * HID + kw;
      RLOAD(aH[i][0], ap, "0");
      RLOAD(aH[i][1], ap, "64");
      RLOAD(aH[i][2], ap, "128");
      RLOAD(aH[i][3], ap, "192");
    }
    asm volatile("s_waitcnt vmcnt(0)" ::: "memory");
    __builtin_amdgcn_sched_barrier(0);

    f32x4 acc[4][2];
#pragma unroll
    for (int i = 0; i < 4; ++i)
#pragma unroll
      for (int n2 = 0; n2 < 2; ++n2) acc[i][n2] = accI[i][n2];

#pragma unroll
    for (int s = 0; s < 4; ++s) {
      const h16x8 b0 = *(const h16x8*)(bbH + s * 512);
      const h16x8 b1 = *(const h16x8*)(bbH + 2048 + s * 512);
#pragma unroll
      for (int i = 0; i < 4; ++i) {
        acc[i][0] = __builtin_amdgcn_mfma_f32_16x16x32_f16(aH[i][s], b0, acc[i][0], 0, 0, 0);
        acc[i][1] = __builtin_amdgcn_mfma_f32_16x16x32_f16(aH[i][s], b1, acc[i][1], 0, 0, 0);
      }
    }

    // ---- 8-way cross-wave reduce, 2 rounds of 2 m-tiles (4 syncthreads) ---
#pragma unroll
    for (int p = 0; p < 2; ++p) {
#pragma unroll
      for (int ii = 0; ii < 2; ++ii) {
        const int i = p * 2 + ii;
#pragma unroll
        for (int n2 = 0; n2 < 2; ++n2)
#pragma unroll
          for (int q = 0; q < 4; ++q) {
            const int r = l16 * 4 + q;                        // 0..15
            const int colS = (n2 * 16 + l15) ^ ((r & 7) << 2);
            plds[ii][wave][r][colS] = acc[i][n2][q];
          }
      }
      __syncthreads();
      if (tid < 256) {
        const int ii = tid >> 7, r = (tid >> 3) & 15, j = tid & 7;
        float gv[4];
#pragma unroll
        for (int gg = 0; gg < 4; ++gg) {
          const int colS = (gg * 8 + j) ^ ((r & 7) << 2);
          float s = bc[gg];
#pragma unroll
          for (int w = 0; w < 8; ++w) s += plds[ii][w][r][colS];
          gv[gg] = s;
        }
        const float ig = 1.f / (1.f + __expf(-gv[0]));
        const float fg = 1.f / (1.f + __expf(-gv[1]));
        const float gt = 1.f - 2.f / (__expf(2.f * gv[2]) + 1.f);
        const float og = 1.f / (1.f + __expf(-gv[3]));
        const float cn = fg * creg2[p] + ig * gt;
        creg2[p] = cn;
        const float th = 1.f - 2.f / (__expf(2.f * cn) + 1.f);
        union { h16 f; unsigned short u; } hb;
        hb.f = (h16)(og * th);
        const int row = (p * 2 + ii) * 16 + r;
        __hip_atomic_store(
            (unsigned short*)&Hout[(size_t)row * HID + j0 + j],
            hb.u, __ATOMIC_RELAXED, __HIP_MEMORY_SCOPE_AGENT);
      }
      __syncthreads();   // drains each wave's vmcnt: h-stores at L3
    }

    // ---- publish step completion: u16 epoch into the compact line ----
    if (tid == 0)
      asm volatile("global_store_short %0, %1, off sc1"
                   :: "v"(my_ep), "v"(t + 1) : "memory");
  }
}

// ---------------------------------------------------------------------------
// out[m][cls] = h[m] . fc_w[cls] + fc_b[cls]. One wave per output.
// ---------------------------------------------------------------------------
__global__ __launch_bounds__(256)
void fc_kernel(const h16* __restrict__ h,
               const float* __restrict__ fw,
               const float* __restrict__ fb,
               float* __restrict__ out)
{
  const int gw = (blockIdx.x * blockDim.x + threadIdx.x) >> 6;
  const int lane = threadIdx.x & 63;
  if (gw >= BATCH * 10) return;
  const int m = gw / 10, cls = gw % 10;
  float s = 0.f;
  for (int k = lane; k < HID; k += 64)
    s += (float)h[(size_t)m * HID + k] * fw[(size_t)cls * HID + k];
#pragma unroll
  for (int off = 32; off; off >>= 1) s += __shfl_down(s, off);
  if (lane == 0) out[m * 10 + cls] = s + fb[cls];
}

// ---------------------------------------------------------------------------
extern "C" void kernel_launch(void* const* d_in, const int* in_sizes, int n_in,
                              void* d_out, int out_size, void* d_ws, size_t ws_size,
                              hipStream_t stream)
{
  const float* x      = (const float*)d_in[0];   // [256][64][1024]
  const float* weight = (const float*)d_in[1];   // [2][2][4096][1024]
  const float* bias   = (const float*)d_in[2];   // [2][2][4096]
  const float* fc_w   = (const float*)d_in[3];   // [10][1024]
  const float* fc_b   = (const float*)d_in[4];   // [10]
  float* out = (float*)d_out;                    // [64][10]

  auto align = [](size_t v) { return (v + 255) & ~(size_t)255; };
  const size_t ep_sz   = 512;                                              // 2x256B
  const size_t x16_sz  = (size_t)S_LEN * BATCH * HID * sizeof(h16);        // 32 MB
  const size_t h0r_sz  = (size_t)RING_D * BATCH * HID * sizeof(h16);       // 512 KB
  const size_t h1r_sz  = (size_t)2 * BATCH * HID * sizeof(h16);            // 256 KB

  char* p = (char*)d_ws;
  unsigned* ep = (unsigned*)p; p += align(ep_sz);
  h16* x16 = (h16*)p; p += align(x16_sz);
  h16* h0r = (h16*)p; p += align(h0r_sz);
  h16* h1r = (h16*)p; p += align(h1r_sz);

  hipMemsetAsync(ep, 0, ep_sz, stream);
  hipMemsetAsync(h0r, 0, h0r_sz, stream);
  hipMemsetAsync(h1r, 0, h1r_sz, stream);

  xconv_kernel<<<dim3(2048), 256, 0, stream>>>(x, x16);

  lstm_persistent<<<dim3(NBLK), dim3(512), 0, stream>>>(
      x16, weight, bias, h0r, h1r, ep);

  // final h of top layer: t = 255 -> h1 ring slot 1
  fc_kernel<<<dim3((BATCH * 10 * 64) / 256), 256, 0, stream>>>(
      h1r + (size_t)BATCH * HID, fc_w, fc_b, out);
}